// Round 10
// baseline (367.172 us; speedup 1.0000x reference)
//
#include <hip/hip_runtime.h>
#include <hip/hip_bf16.h>

// PropNet on MI355X — fp32 in/out, bf16 MFMA compute, fused row-local layers.
// B=4, N=1024, E=8192, NF_IN=32, H=128, NF_OUT=3, pstep=2 (fixed).
//
// R10: latency-hiding on the LDS-staged edge kernels (R9 = 363.6 us).
//  - k_eprop: double-buffered weight staging (wbuf[2][32KB]; stage group g+1
//    before computing group g) + all 12 A-fragments prefetched to registers
//    at kernel entry. No occupancy change (grid already caps at 2 blocks/CU).
//  - k_enc edge path: double-buffered staging (wbuf[2][16KB], 5 pipelined
//    stages, stage issued before compute each step) + x[rr]/x[rs] prefetch.
// Numerics identical to R9 (same rounding points) -> absmax 4.88e-4.
// Kept: k_prep, CSR aggregation, k_nprop/k_npropred, bf16 shadows.

typedef unsigned short u16;
typedef __attribute__((ext_vector_type(8))) __bf16 bf16x8;
typedef __attribute__((ext_vector_type(4))) float f32x4;

#define N_    1024
#define BN    4096      // B*N
#define BE    32768     // B*E
#define LOG_E 13
#define H_    128
#define LSTR  132       // LDS row stride (floats, node path)
#define ECAP  64        // max edges per node in CSR (P(deg>64) ~ 0)
#define ASTR  136       // LDS u16 row stride for bf16 tiles (16B-aligned rows)

__device__ __forceinline__ u16 f2bf(float f) {
    __bf16 h = (__bf16)f;
    return __builtin_bit_cast(u16, h);
}

__device__ __forceinline__ bf16x8 cvt8(float4 f0, float4 f1) {
    bf16x8 a;
    a[0] = (__bf16)f0.x; a[1] = (__bf16)f0.y; a[2] = (__bf16)f0.z; a[3] = (__bf16)f0.w;
    a[4] = (__bf16)f1.x; a[5] = (__bf16)f1.y; a[6] = (__bf16)f1.z; a[7] = (__bf16)f1.w;
    return a;
}

// A-fragment (8 contiguous k) from fp32 global/LDS pointer (32B-aligned).
__device__ __forceinline__ bf16x8 a_from_f32(const float* p) {
    float4 f0 = *(const float4*)p;
    float4 f1 = *(const float4*)(p + 4);
    return cvt8(f0, f1);
}

// A-fragment from a per-block fp32 LDS tile for K-chunk c, row r (node path).
__device__ __forceinline__ bf16x8 a_from_lds(const float* lds, int r, int quad, int c) {
    return a_from_f32(lds + r * LSTR + c * 32 + quad * 8);
}

// ---- MFMA micro-tiles ------------------------------------------------------
// One K=32 chunk (LDS-staged B), all 8 column-tiles. cc = chunk idx in wbuf.
__device__ __forceinline__ void mm8L(const u16* wb, int cc, bf16x8 a,
                                     f32x4* acc, int lane) {
    const u16* wp = wb + cc * 4096;
    #pragma unroll
    for (int nt = 0; nt < 8; ++nt) {
        bf16x8 bw = *(const bf16x8*)(wp + (nt * 64 + lane) * 8);
        acc[nt] = __builtin_amdgcn_mfma_f32_16x16x32_bf16(a, bw, acc[nt], 0, 0, 0);
    }
}

// One K=32 chunk (global B), 2 column-tiles starting at ntb.
__device__ __forceinline__ void mm2(const u16* __restrict__ Wf, int c, int ntb,
                                    bf16x8 a, f32x4* acc, int lane) {
    const u16* wp = Wf + ((size_t)c * 8) * 64 * 8;
    #pragma unroll
    for (int nt = 0; nt < 2; ++nt) {
        bf16x8 bw = *(const bf16x8*)(wp + (size_t)((ntb + nt) * 64 + lane) * 8);
        acc[nt] = __builtin_amdgcn_mfma_f32_16x16x32_bf16(a, bw, acc[nt], 0, 0, 0);
    }
}

__device__ __forceinline__ void zacc8(f32x4* acc) {
    #pragma unroll
    for (int t = 0; t < 8; ++t) acc[t] = (f32x4){0.f, 0.f, 0.f, 0.f};
}
__device__ __forceinline__ void zacc2(f32x4* acc) {
    acc[0] = (f32x4){0.f, 0.f, 0.f, 0.f};
    acc[1] = (f32x4){0.f, 0.f, 0.f, 0.f};
}

// cooperative 16B-unit copy: n16 units, 256 threads
__device__ __forceinline__ void stage_w(u16* dst, const u16* __restrict__ src,
                                        int n16, int tid) {
    for (int t = tid; t < n16; t += 256)
        *(bf16x8*)(dst + t * 8) = *(const bf16x8*)(src + t * 8);
}

// bias+ReLU epilogue into per-wave bf16 tile (stride ASTR).
__device__ __forceinline__ void epi8_bf(u16* t, const f32x4* acc,
                                        const float* __restrict__ bias,
                                        int quad, int m) {
    #pragma unroll
    for (int nt = 0; nt < 8; ++nt) {
        float bv = bias[nt * 16 + m];
        #pragma unroll
        for (int i = 0; i < 4; ++i)
            t[(quad * 4 + i) * ASTR + nt * 16 + m] =
                f2bf(fmaxf(acc[nt][i] + bv, 0.f));
    }
}

// bias+ReLU epilogue into fp32 LDS: 2 column-tiles at ntb (node path).
__device__ __forceinline__ void epi2_lds(float* lds, const f32x4* acc,
                                         const float* __restrict__ bias,
                                         int quad, int m, int ntb) {
    #pragma unroll
    for (int nt = 0; nt < 2; ++nt) {
        int col = (ntb + nt) * 16 + m;
        float bv = bias[col];
        #pragma unroll
        for (int i = 0; i < 4; ++i)
            lds[(quad * 4 + i) * LSTR + col] = fmaxf(acc[nt][i] + bv, 0.f);
    }
}

// ---------------------------------------------------------------------------
// k_prep: extract (blocks 0..16383) ∪ weight permutation (blocks 16384..).
// deg must be zeroed (hipMemsetAsync) BEFORE this kernel.
// ---------------------------------------------------------------------------
struct WDesc { const float* src; u16* dst; int K; };
struct WPack { WDesc d[10]; };

__global__ __launch_bounds__(256) void k_prep(WPack P,
                                              const float* __restrict__ Rr,
                                              const float* __restrict__ Rs,
                                              int* __restrict__ recv,
                                              int* __restrict__ send,
                                              int* __restrict__ deg,
                                              int* __restrict__ eidx) {
    int bx = blockIdx.x;
    if (bx >= 16384) {            // ---- weight permutation part ----
        int t = bx - 16384;       // 0..1919, 192 blocks per weight
        WDesc d = P.d[t / 192];
        int i = (t % 192) * 256 + threadIdx.x;
        if (i >= d.K * 128) return;
        int j    = i & 7;
        int lane = (i >> 3) & 63;
        int nt   = (i >> 9) & 7;
        int c    = i >> 12;
        int k = c * 32 + (lane >> 4) * 8 + j;
        int n = nt * 16 + (lane & 15);
        d.dst[i] = f2bf(d.src[k * 128 + n]);
        return;
    }
    // ---- one-hot -> index + receiver CSR part ----
    int wave = threadIdx.x >> 6, lane = threadIdx.x & 63;
    int g = bx * 4 + wave;        // < 2*BE
    const float* src;
    int* dst;
    if (g < BE) { src = Rr + (size_t)g * N_;        dst = recv + g; }
    else        { src = Rs + (size_t)(g - BE) * N_; dst = send + (g - BE); }
    int idx = 0;
    bool done = false;
    #pragma unroll
    for (int it = 0; it < 4; ++it) {
        if (!done) {
            int base = it * 256 + lane * 4;
            float4 v = *(const float4*)(src + base);
            int found = -1;
            if      (v.x != 0.f) found = base;
            else if (v.y != 0.f) found = base + 1;
            else if (v.z != 0.f) found = base + 2;
            else if (v.w != 0.f) found = base + 3;
            unsigned long long msk = __ballot(found >= 0);
            if (msk) {
                int sl = __ffsll((long long)msk) - 1;
                idx = __shfl(found, sl, 64);
                done = true;
            }
        }
    }
    if (lane == 0) {
        *dst = idx;
        if (g < BE) {             // receiver side: CSR build
            int node = (g >> LOG_E) * N_ + idx;
            int pos = atomicAdd(deg + node, 1);
            if (pos < ECAP) eidx[node * ECAP + pos] = g;
        }
    }
}

// ---------------------------------------------------------------------------
// k_enc: edge encoder (blocks 0..511, 64 rows/block, double-buffered LDS
//        weight staging) ∪ node encoder (blocks 512..767, 4-wave col-split).
// 256 threads / 4 waves.
// ---------------------------------------------------------------------------
__global__ __launch_bounds__(256) void k_enc(
    const float* __restrict__ x,
    const int* __restrict__ recv, const int* __restrict__ send,
    const u16* __restrict__ nW0, const float* __restrict__ nb0,
    const u16* __restrict__ nW1, const float* __restrict__ nb1,
    const u16* __restrict__ nW2, const float* __restrict__ nb2,
    const u16* __restrict__ eW0, const float* __restrict__ eb0,
    const u16* __restrict__ eW1, const float* __restrict__ eb1,
    const u16* __restrict__ eW2, const float* __restrict__ eb2,
    float* __restrict__ nenc_f, u16* __restrict__ nenc_bf,
    u16* __restrict__ eenc)
{
    __shared__ union U {
        struct { u16 wb[2][8192]; u16 tile[4][2][16 * ASTR]; } e;  // 32+34.8 KB
        struct { float lds[2][16 * LSTR]; } n;                     // 16.9 KB
    } sm;
    int tid = threadIdx.x, lane = tid & 63, w = tid >> 6;
    int m = lane & 15, quad = lane >> 4;

    if (blockIdx.x < 512) {       // ======== edge encoder ========
        int myrow16 = blockIdx.x * 64 + w * 16;
        int e = myrow16 + m, b = e >> LOG_E;
        long rr = (long)b * N_ + recv[e];
        long rs = (long)b * N_ + send[e];
        u16* t0 = sm.e.tile[w][0];
        u16* t1 = sm.e.tile[w][1];
        f32x4 acc[8];

        // prefetch layer-0 A fragments (overlaps with W0 staging)
        bf16x8 a_rr = a_from_f32(x + rr * 32 + quad * 8);
        bf16x8 a_rs = a_from_f32(x + rs * 32 + quad * 8);

        // ---- stage W0 (16 KB, 2 chunks) ----
        stage_w(sm.e.wb[0], eW0, 1024, tid);
        __syncthreads();

        // ---- layer 0 compute; stage W1 half0 into wb[1] ----
        stage_w(sm.e.wb[1], eW1, 1024, tid);
        zacc8(acc);
        mm8L(sm.e.wb[0], 0, a_rr, acc, lane);
        mm8L(sm.e.wb[0], 1, a_rs, acc, lane);
        epi8_bf(t0, acc, eb0, quad, m);
        __syncthreads();

        // ---- layer 1 half0 from wb[1]; stage W1 half1 into wb[0] ----
        stage_w(sm.e.wb[0], eW1 + 8192, 1024, tid);
        zacc8(acc);
        mm8L(sm.e.wb[1], 0, *(const bf16x8*)(t0 + m * ASTR + 0 * 32 + quad * 8), acc, lane);
        mm8L(sm.e.wb[1], 1, *(const bf16x8*)(t0 + m * ASTR + 1 * 32 + quad * 8), acc, lane);
        __syncthreads();

        // ---- layer 1 half1 from wb[0]; stage W2 half0 into wb[1] ----
        stage_w(sm.e.wb[1], eW2, 1024, tid);
        mm8L(sm.e.wb[0], 0, *(const bf16x8*)(t0 + m * ASTR + 2 * 32 + quad * 8), acc, lane);
        mm8L(sm.e.wb[0], 1, *(const bf16x8*)(t0 + m * ASTR + 3 * 32 + quad * 8), acc, lane);
        epi8_bf(t1, acc, eb1, quad, m);
        __syncthreads();

        // ---- layer 2 half0 from wb[1]; stage W2 half1 into wb[0] ----
        stage_w(sm.e.wb[0], eW2 + 8192, 1024, tid);
        zacc8(acc);
        mm8L(sm.e.wb[1], 0, *(const bf16x8*)(t1 + m * ASTR + 0 * 32 + quad * 8), acc, lane);
        mm8L(sm.e.wb[1], 1, *(const bf16x8*)(t1 + m * ASTR + 1 * 32 + quad * 8), acc, lane);
        __syncthreads();

        // ---- layer 2 half1 from wb[0] ----
        mm8L(sm.e.wb[0], 0, *(const bf16x8*)(t1 + m * ASTR + 2 * 32 + quad * 8), acc, lane);
        mm8L(sm.e.wb[0], 1, *(const bf16x8*)(t1 + m * ASTR + 3 * 32 + quad * 8), acc, lane);
        epi8_bf(t0, acc, eb2, quad, m);

        // coalesced bf16 store of this wave's 16 rows (u32 pairs)
        #pragma unroll
        for (int t = 0; t < 16; ++t)
            *(unsigned*)(eenc + (size_t)(myrow16 + t) * H_ + lane * 2) =
                *(const unsigned*)(t0 + t * ASTR + lane * 2);
        return;
    }

    // ======== node encoder (4 waves col-split, ntb = w*2) ========
    int row16 = (blockIdx.x - 512) * 16, ntb = w * 2;
    f32x4 acc[2];

    zacc2(acc);
    mm2(nW0, 0, ntb, a_from_f32(x + (size_t)(row16 + m) * 32 + quad * 8), acc, lane);
    epi2_lds(sm.n.lds[0], acc, nb0, quad, m, ntb);
    __syncthreads();

    zacc2(acc);
    #pragma unroll
    for (int c = 0; c < 4; ++c)
        mm2(nW1, c, ntb, a_from_lds(sm.n.lds[0], m, quad, c), acc, lane);
    epi2_lds(sm.n.lds[1], acc, nb1, quad, m, ntb);
    __syncthreads();

    zacc2(acc);
    #pragma unroll
    for (int c = 0; c < 4; ++c)
        mm2(nW2, c, ntb, a_from_lds(sm.n.lds[1], m, quad, c), acc, lane);
    epi2_lds(sm.n.lds[0], acc, nb2, quad, m, ntb);
    __syncthreads();

    #pragma unroll
    for (int t = 0; t < 8; ++t) {
        int flat = t * 256 + tid, r = flat >> 7, col = flat & 127;
        nenc_f[(size_t)(row16 + r) * H_ + col] = sm.n.lds[0][r * LSTR + col];
    }
    #pragma unroll
    for (int t = 0; t < 4; ++t) {
        int p = t * 256 + tid, r = p >> 6, c2 = (p & 63) * 2;
        u16 lo = f2bf(sm.n.lds[0][r * LSTR + c2]);
        u16 hi = f2bf(sm.n.lds[0][r * LSTR + c2 + 1]);
        *(unsigned*)(nenc_bf + (size_t)(row16 + r) * H_ + c2) =
            (unsigned)lo | ((unsigned)hi << 16);
    }
}

// ---------------------------------------------------------------------------
// Prop edge layer: relu(concat(eenc, eff[recv], eff[send]) @ epW + epb)
// -> per-edge effect buffer. 512 blocks x 4 waves, 16 rows/wave.
// Double-buffered weight staging + register-prefetched A fragments.
// ---------------------------------------------------------------------------
__global__ __launch_bounds__(256) void k_eprop(
    const u16* __restrict__ eenc, const u16* __restrict__ eff_bf,
    const int* __restrict__ recv, const int* __restrict__ send,
    const u16* __restrict__ Wf, const float* __restrict__ bias,
    float* __restrict__ edge_eff)
{
    __shared__ u16 wbuf[2][16384];   // 2 x 32 KB (4 K-chunks each)
    int tid = threadIdx.x, lane = tid & 63, w = tid >> 6;
    int m = lane & 15, quad = lane >> 4;
    int myrow16 = blockIdx.x * 64 + w * 16;
    int e = myrow16 + m;
    long rr = ((long)(e >> LOG_E) * N_ + recv[e]) * H_;
    long rs = ((long)(e >> LOG_E) * N_ + send[e]) * H_;

    // prefetch all 12 A fragments (latency hides under weight staging)
    bf16x8 af[12];
    #pragma unroll
    for (int c = 0; c < 4; ++c) {
        af[c]     = *(const bf16x8*)(eenc + (size_t)e * H_ + c * 32 + quad * 8);
        af[4 + c] = *(const bf16x8*)(eff_bf + rr + c * 32 + quad * 8);
        af[8 + c] = *(const bf16x8*)(eff_bf + rs + c * 32 + quad * 8);
    }

    f32x4 acc[8];
    zacc8(acc);

    stage_w(wbuf[0], Wf, 2048, tid);
    __syncthreads();
    #pragma unroll
    for (int g = 0; g < 3; ++g) {
        if (g < 2) stage_w(wbuf[(g + 1) & 1], Wf + (g + 1) * 16384, 2048, tid);
        #pragma unroll
        for (int c = 0; c < 4; ++c)
            mm8L(wbuf[g & 1], c, af[g * 4 + c], acc, lane);
        __syncthreads();
    }

    #pragma unroll
    for (int nt = 0; nt < 8; ++nt) {
        int col = nt * 16 + m;
        float bv = bias[col];
        #pragma unroll
        for (int i = 0; i < 4; ++i)
            edge_eff[(size_t)(myrow16 + quad * 4 + i) * H_ + col] =
                fmaxf(acc[nt][i] + bv, 0.f);
    }
}

// ---------------------------------------------------------------------------
// CSR gather-aggregate of incident edge effects into a bf16 LDS tile.
// 256 threads = 16 nodes x 16 col-groups.
// ---------------------------------------------------------------------------
__device__ __forceinline__ void gather_agg(u16* aggl, int row16, int tid, int lane,
                                           const float* __restrict__ edge_eff,
                                           const int* __restrict__ deg,
                                           const int* __restrict__ eidx) {
    int nd = tid >> 4, l = tid & 15;
    int node = row16 + nd;
    int dg = deg[node]; dg = dg < ECAP ? dg : ECAP;
    int ev = eidx[node * ECAP + l];          // preloaded slot l of the list
    int base = lane & 48;                    // 16-lane group start in wave
    float s[8] = {0.f, 0.f, 0.f, 0.f, 0.f, 0.f, 0.f, 0.f};
    int d16 = dg < 16 ? dg : 16;
    int t = 0;
    for (; t + 1 < d16; t += 2) {            // unroll-2: loads pipelined
        int e0 = __shfl(ev, base | t, 64);
        int e1 = __shfl(ev, base | (t + 1), 64);
        const float* p0 = edge_eff + (size_t)e0 * H_ + l * 8;
        const float* p1 = edge_eff + (size_t)e1 * H_ + l * 8;
        float4 a0 = *(const float4*)p0, b0 = *(const float4*)(p0 + 4);
        float4 a1 = *(const float4*)p1, b1 = *(const float4*)(p1 + 4);
        s[0] += a0.x + a1.x; s[1] += a0.y + a1.y;
        s[2] += a0.z + a1.z; s[3] += a0.w + a1.w;
        s[4] += b0.x + b1.x; s[5] += b0.y + b1.y;
        s[6] += b0.z + b1.z; s[7] += b0.w + b1.w;
    }
    if (t < d16) {
        int e0 = __shfl(ev, base | t, 64);
        const float* p0 = edge_eff + (size_t)e0 * H_ + l * 8;
        float4 a0 = *(const float4*)p0, b0 = *(const float4*)(p0 + 4);
        s[0] += a0.x; s[1] += a0.y; s[2] += a0.z; s[3] += a0.w;
        s[4] += b0.x; s[5] += b0.y; s[6] += b0.z; s[7] += b0.w;
        ++t;
    }
    for (; t < dg; ++t) {                    // rare deg>16 tail
        int e0 = eidx[node * ECAP + t];
        const float* p0 = edge_eff + (size_t)e0 * H_ + l * 8;
        float4 a0 = *(const float4*)p0, b0 = *(const float4*)(p0 + 4);
        s[0] += a0.x; s[1] += a0.y; s[2] += a0.z; s[3] += a0.w;
        s[4] += b0.x; s[5] += b0.y; s[6] += b0.z; s[7] += b0.w;
    }
    bf16x8 o;
    #pragma unroll
    for (int j = 0; j < 8; ++j) o[j] = (__bf16)s[j];
    *(bf16x8*)(aggl + nd * ASTR + l * 8) = o;
}

// ---------------------------------------------------------------------------
// Prop node layer (step 1): gather + relu(concat(nenc, agg) @ npW + npb + eff)
// -> nef1 fp32 + bf16. 4 waves/block, column-split (ntb = w*2).
// ---------------------------------------------------------------------------
__global__ __launch_bounds__(256) void k_nprop(
    const u16* __restrict__ nenc_bf, const float* __restrict__ edge_eff,
    const int* __restrict__ deg, const int* __restrict__ eidx,
    const float* __restrict__ eff_f,
    const u16* __restrict__ Wf, const float* __restrict__ bias,
    float* __restrict__ nout_f, u16* __restrict__ nout_bf)
{
    __shared__ u16 aggl[16 * ASTR];
    int tid = threadIdx.x, lane = tid & 63, w = tid >> 6;
    int m = lane & 15, quad = lane >> 4;
    int row16 = blockIdx.x * 16;

    gather_agg(aggl, row16, tid, lane, edge_eff, deg, eidx);
    __syncthreads();

    int row = row16 + m, ntb = w * 2;
    f32x4 acc[2];
    zacc2(acc);
    #pragma unroll
    for (int c = 0; c < 4; ++c)
        mm2(Wf, c, ntb,
            *(const bf16x8*)(nenc_bf + (size_t)row * H_ + c * 32 + quad * 8), acc, lane);
    #pragma unroll
    for (int c = 0; c < 4; ++c)
        mm2(Wf, 4 + c, ntb,
            *(const bf16x8*)(aggl + m * ASTR + c * 32 + quad * 8), acc, lane);

    #pragma unroll
    for (int nt = 0; nt < 2; ++nt) {
        int col = (ntb + nt) * 16 + m;
        float bv = bias[col];
        #pragma unroll
        for (int i = 0; i < 4; ++i) {
            int r = row16 + quad * 4 + i;
            float v = fmaxf(acc[nt][i] + bv + eff_f[(size_t)r * H_ + col], 0.f);
            nout_f[(size_t)r * H_ + col] = v;
            nout_bf[(size_t)r * H_ + col] = f2bf(v);
        }
    }
}

// ---------------------------------------------------------------------------
// Prop node layer (step 2) FUSED with the predictor. Row-local chain:
// gather -> np GEMM (+residual, relu) -> pp0 -> pp1 -> [128,3] head -> out.
// ---------------------------------------------------------------------------
__global__ __launch_bounds__(256) void k_npropred(
    const u16* __restrict__ nenc_bf, const float* __restrict__ edge_eff,
    const int* __restrict__ deg, const int* __restrict__ eidx,
    const float* __restrict__ eff_f,
    const u16* __restrict__ Wnp, const float* __restrict__ bnp,
    const u16* __restrict__ Wp0, const float* __restrict__ bp0,
    const u16* __restrict__ Wp1, const float* __restrict__ bp1,
    const float* __restrict__ W2, const float* __restrict__ b2,
    float* __restrict__ out)
{
    __shared__ u16 aggl[16 * ASTR];
    __shared__ u16 vl[16 * ASTR];            // nef2 tile (bf16)
    __shared__ u16 h1[16 * ASTR];            // pp layer-0 output (bf16)
    __shared__ float h2[16 * LSTR];          // pp layer-1 output (fp32)
    int tid = threadIdx.x, lane = tid & 63, w = tid >> 6;
    int m = lane & 15, quad = lane >> 4;
    int row16 = blockIdx.x * 16;

    gather_agg(aggl, row16, tid, lane, edge_eff, deg, eidx);
    __syncthreads();

    int row = row16 + m, ntb = w * 2;
    f32x4 acc[2];

    // ---- np layer: v = relu(concat(nenc, agg) @ Wnp + bnp + eff) ----
    zacc2(acc);
    #pragma unroll
    for (int c = 0; c < 4; ++c)
        mm2(Wnp, c, ntb,
            *(const bf16x8*)(nenc_bf + (size_t)row * H_ + c * 32 + quad * 8), acc, lane);
    #pragma unroll
    for (int c = 0; c < 4; ++c)
        mm2(Wnp, 4 + c, ntb,
            *(const bf16x8*)(aggl + m * ASTR + c * 32 + quad * 8), acc, lane);
    #pragma unroll
    for (int nt = 0; nt < 2; ++nt) {
        int col = (ntb + nt) * 16 + m;
        float bv = bnp[col];
        #pragma unroll
        for (int i = 0; i < 4; ++i) {
            int r = quad * 4 + i;
            float v = fmaxf(acc[nt][i] + bv + eff_f[(size_t)(row16 + r) * H_ + col], 0.f);
            vl[r * ASTR + col] = f2bf(v);
        }
    }
    __syncthreads();

    // ---- pp layer 0 (K=256): A = [nenc | v] ----
    zacc2(acc);
    #pragma unroll
    for (int c = 0; c < 4; ++c)
        mm2(Wp0, c, ntb,
            *(const bf16x8*)(nenc_bf + (size_t)row * H_ + c * 32 + quad * 8), acc, lane);
    #pragma unroll
    for (int c = 0; c < 4; ++c)
        mm2(Wp0, 4 + c, ntb,
            *(const bf16x8*)(vl + m * ASTR + c * 32 + quad * 8), acc, lane);
    #pragma unroll
    for (int nt = 0; nt < 2; ++nt) {
        int col = (ntb + nt) * 16 + m;
        float bv = bp0[col];
        #pragma unroll
        for (int i = 0; i < 4; ++i)
            h1[(quad * 4 + i) * ASTR + col] = f2bf(fmaxf(acc[nt][i] + bv, 0.f));
    }
    __syncthreads();

    // ---- pp layer 1 (K=128) ----
    zacc2(acc);
    #pragma unroll
    for (int c = 0; c < 4; ++c)
        mm2(Wp1, c, ntb,
            *(const bf16x8*)(h1 + m * ASTR + c * 32 + quad * 8), acc, lane);
    #pragma unroll
    for (int nt = 0; nt < 2; ++nt) {
        int col = (ntb + nt) * 16 + m;
        float bv = bp1[col];
        #pragma unroll
        for (int i = 0; i < 4; ++i)
            h2[(quad * 4 + i) * LSTR + col] = fmaxf(acc[nt][i] + bv, 0.f);
    }
    __syncthreads();

    // ---- head: out[r,col] = h2[r,:] . W2[:,col] + b2[col] ----
    if (w == 0) {
        int r = lane & 15, col = lane >> 4;
        if (col < 3) {
            float s = 0.f;
            #pragma unroll 8
            for (int k = 0; k < 128; ++k)
                s += h2[r * LSTR + k] * W2[k * 3 + col];
            out[(size_t)(row16 + r) * 3 + col] = s + b2[col];
        }
    }
}

// ---------------------------------------------------------------------------
extern "C" void kernel_launch(void* const* d_in, const int* in_sizes, int n_in,
                              void* d_out, int out_size, void* d_ws, size_t ws_size,
                              hipStream_t stream) {
    (void)in_sizes; (void)n_in; (void)out_size; (void)ws_size;

    const float* x    = (const float*)d_in[0];
    const float* Rr   = (const float*)d_in[1];
    const float* Rs   = (const float*)d_in[2];
    // d_in[3] = pstep (==2, hard-coded)
    const float* neW0 = (const float*)d_in[4];  const float* neb0 = (const float*)d_in[5];
    const float* neW1 = (const float*)d_in[6];  const float* neb1 = (const float*)d_in[7];
    const float* neW2 = (const float*)d_in[8];  const float* neb2 = (const float*)d_in[9];
    const float* eeW0 = (const float*)d_in[10]; const float* eeb0 = (const float*)d_in[11];
    const float* eeW1 = (const float*)d_in[12]; const float* eeb1 = (const float*)d_in[13];
    const float* eeW2 = (const float*)d_in[14]; const float* eeb2 = (const float*)d_in[15];
    const float* npW  = (const float*)d_in[16]; const float* npb  = (const float*)d_in[17];
    const float* epW  = (const float*)d_in[18]; const float* epb  = (const float*)d_in[19];
    const float* ppW0 = (const float*)d_in[20]; const float* ppb0 = (const float*)d_in[21];
    const float* ppW1 = (const float*)d_in[22]; const float* ppb1 = (const float*)d_in[23];
    const float* ppW2 = (const float*)d_in[24]; const float* ppb2 = (const float*)d_in[25];

    char* ws = (char*)d_ws;
    size_t off = 0;
    auto alloc = [&](size_t bytes) -> char* {
        char* p = ws + off;
        off += (bytes + 255) & ~(size_t)255;
        return p;
    };

    u16* f_neW0 = (u16*)alloc(32  * 128 * 2);
    u16* f_neW1 = (u16*)alloc(128 * 128 * 2);
    u16* f_neW2 = (u16*)alloc(128 * 128 * 2);
    u16* f_eeW0 = (u16*)alloc(64  * 128 * 2);
    u16* f_eeW1 = (u16*)alloc(128 * 128 * 2);
    u16* f_eeW2 = (u16*)alloc(128 * 128 * 2);
    u16* f_epW  = (u16*)alloc(384 * 128 * 2);
    u16* f_npW  = (u16*)alloc(256 * 128 * 2);
    u16* f_ppW0 = (u16*)alloc(256 * 128 * 2);
    u16* f_ppW1 = (u16*)alloc(128 * 128 * 2);
    int*   recv = (int*)alloc(BE * 4);
    int*   send = (int*)alloc(BE * 4);
    int*   deg  = (int*)alloc(BN * 4);
    int*   eidx = (int*)alloc((size_t)BN * ECAP * 4);
    float* nenc_f  = (float*)alloc((size_t)BN * H_ * 4);
    u16*   nenc_bf = (u16*)alloc((size_t)BN * H_ * 2);
    float* nef1_f  = (float*)alloc((size_t)BN * H_ * 4);
    u16*   nef1_bf = (u16*)alloc((size_t)BN * H_ * 2);
    float* edge_eff = (float*)alloc((size_t)BE * H_ * 4);
    u16*   eenc = (u16*)alloc((size_t)BE * H_ * 2);

    WPack P;
    P.d[0] = {neW0, f_neW0, 32};
    P.d[1] = {neW1, f_neW1, 128};
    P.d[2] = {neW2, f_neW2, 128};
    P.d[3] = {eeW0, f_eeW0, 64};
    P.d[4] = {eeW1, f_eeW1, 128};
    P.d[5] = {eeW2, f_eeW2, 128};
    P.d[6] = {epW,  f_epW,  384};
    P.d[7] = {npW,  f_npW,  256};
    P.d[8] = {ppW0, f_ppW0, 256};
    P.d[9] = {ppW1, f_ppW1, 128};

    // 0) zero CSR degree counters (graph-capturable memset)
    hipMemsetAsync(deg, 0, BN * 4, stream);

    // 1) extract ∪ weight permutation
    k_prep<<<16384 + 1920, 256, 0, stream>>>(P, Rr, Rs, recv, send, deg, eidx);

    // 2) edge encoder (double-buffered staging) ∪ node encoder
    k_enc<<<512 + 256, 256, 0, stream>>>(x, recv, send,
                                         f_neW0, neb0, f_neW1, neb1, f_neW2, neb2,
                                         f_eeW0, eeb0, f_eeW1, eeb1, f_eeW2, eeb2,
                                         nenc_f, nenc_bf, eenc);

    // 3) propagation steps (pstep = 2); eprop double-buffered, 64 rows/block
    k_eprop<<<BE / 64, 256, 0, stream>>>(eenc, nenc_bf, recv, send, f_epW, epb, edge_eff);
    k_nprop<<<BN / 16, 256, 0, stream>>>(nenc_bf, edge_eff, deg, eidx, nenc_f,
                                         f_npW, npb, nef1_f, nef1_bf);
    k_eprop<<<BE / 64, 256, 0, stream>>>(eenc, nef1_bf, recv, send, f_epW, epb, edge_eff);
    k_npropred<<<BN / 16, 256, 0, stream>>>(nenc_bf, edge_eff, deg, eidx, nef1_f,
                                            f_npW, npb, f_ppW0, ppb0, f_ppW1, ppb1,
                                            ppW2, ppb2, (float*)d_out);
}